// Round 11
// baseline (128.393 us; speedup 1.0000x reference)
//
#include <hip/hip_runtime.h>
#include <hip/hip_cooperative_groups.h>
#include <math.h>

namespace cg = cooperative_groups;

#define T_LEN   40000
#define BATCH   64
#define RESET_T 30000
#define SUB     16
// regime 1: steps 1..29999 -> 1875 sub-chunks of 16 (1874 full, last = 15)
// regime 2: steps 30000..39999 -> 625 sub-chunks of 16 (all full)
#define NS1     1875
#define L1_LAST 15
#define NS2     625
#define NS      (NS1 + NS2)
// scan groups: 4 subs each (64 steps); groups 0..467 full, group 468 = 3 subs (47 steps)
#define NGFULL  468
#define NROUNDS 9
#define PI_D    3.14159265358979323846

#define NBLK    256
#define NTHR    512
#define NTOT    (NBLK * NTHR)   // 131072 threads

// uniform table in d_ws (doubles):
#define T_A16   0      // 3 mats: A^16, A^32, A^48
#define T_M64   48     // 9 mats: (A^64)^(2^r), r=0..8
#define T_A15   192    // 1 mat: A^15
#define T_LAM   208    // 2 osc * 10 * (re,im) = 40
#define T_TOTAL 248

// d_out layout in FLOATS (complex outputs validated as real part only):
#define Y_SIZE  ((size_t)BATCH * T_LEN * 2)
#define B_OFF   (Y_SIZE)
#define A_OFF   (B_OFF + T_LEN)
#define YS_OFF  (A_OFF + T_LEN)

struct Params { double alpha, beta, g0, g1, delta, k; };

__device__ __forceinline__ Params make_params(double c, double th0, double th1,
                                              double a, double b) {
    double inva = 1.0 / (1.0 + a);
    double bb   = b / (1.0 + b);
    Params p;
    p.alpha = 1.0 + c * (inva - 1.0);
    p.beta  = 1.0 + c * (inva - 1.0 + bb);
    p.g0    = c * inva * th0;
    p.g1    = c * inva * th1;
    p.delta = c * bb;
    p.k     = c * bb;
    return p;
}

__device__ __forceinline__ void get_consts(const float* tau, const float* omega,
                                           double& c, double& th0, double& th1) {
    double tv = (double)tau[0];
    c   = 0.1 / tv;
    th0 = 2.0 * PI_D * tv * (double)omega[0];
    th1 = 2.0 * PI_D * tv * (double)omega[1];
}

__device__ __forceinline__ void step(const Params& P, double& R0, double& I0,
                                     double& R1, double& I1, double z0, double z1) {
    double nR0 = P.alpha * R0 - P.g0 * I0 - P.delta * R1 + P.k * z0;
    double nI0 = P.g0 * R0 + P.beta * I0;
    double nR1 = P.alpha * R1 - P.g1 * I1 - P.delta * R0 + P.k * z1;
    double nI1 = P.g1 * R1 + P.beta * I1;
    R0 = nR0; I0 = nI0; R1 = nR1; I1 = nI1;
}

__device__ __forceinline__ void matmul4(const double* A, const double* B, double* C) {
    for (int i = 0; i < 4; ++i)
        for (int jj = 0; jj < 4; ++jj) {
            double s = 0.0;
            for (int l = 0; l < 4; ++l) s += A[i * 4 + l] * B[l * 4 + jj];
            C[i * 4 + jj] = s;
        }
}

__device__ void build_A(const Params& P, double* A) {
    A[0]  = P.alpha; A[1]  = -P.g0;  A[2]  = -P.delta; A[3]  = 0.0;
    A[4]  = P.g0;    A[5]  = P.beta; A[6]  = 0.0;      A[7]  = 0.0;
    A[8]  = -P.delta;A[9]  = 0.0;    A[10] = P.alpha;  A[11] = -P.g1;
    A[12] = 0.0;     A[13] = 0.0;    A[14] = P.g1;     A[15] = P.beta;
}

// ================= single fused cooperative kernel =================
__global__ __launch_bounds__(NTHR) void fused_all(const float* __restrict__ X,
        const float* tau, const float* omega, const float* a0f, const float* b0f,
        double* __restrict__ p_ws, double* __restrict__ t_ws,
        double* __restrict__ s_ws, double* __restrict__ invn,
        float* __restrict__ b_out, float* __restrict__ a_out,
        float* __restrict__ y_out, float* __restrict__ ysum_out) {
    __shared__ double v[NGFULL * 5];      // scan array, stride 5 (bank-conflict-free)
    __shared__ double Tl[T_TOTAL];
    __shared__ double send1[4];

    cg::grid_group grid = cg::this_grid();
    const int tid = blockIdx.x * NTHR + threadIdx.x;

    double c, th0, th1; get_consts(tau, omega, c, th0, th1);
    Params P1 = make_params(c, th0, th1, (double)a0f[0], (double)b0f[0]);

    // ---------------- Phase A: b/a fill, table build, 16-step partials ----------------
    if (tid < T_LEN) {
        b_out[tid] = (tid < RESET_T) ? b0f[0] : 0.0f;
        a_out[tid] = (tid < RESET_T) ? a0f[0] : 0.0f;
    }
    if (tid == 0) {
        double A1[16], A2m[16], A4m[16], A8m[16], tA12[16], tA14[16], tA15[16];
        build_A(P1, A1);
        matmul4(A1, A1, A2m);
        matmul4(A2m, A2m, A4m);
        matmul4(A4m, A4m, A8m);
        matmul4(A8m, A8m, &t_ws[T_A16]);                         // A16
        matmul4(&t_ws[T_A16], &t_ws[T_A16], &t_ws[T_A16+16]);    // A32
        matmul4(&t_ws[T_A16+16], &t_ws[T_A16], &t_ws[T_A16+32]); // A48
        matmul4(&t_ws[T_A16+32], &t_ws[T_A16], &t_ws[T_M64]);    // A64
        for (int r = 1; r < NROUNDS; ++r)
            matmul4(&t_ws[T_M64 + (r-1)*16], &t_ws[T_M64 + (r-1)*16],
                    &t_ws[T_M64 + r*16]);
        matmul4(A8m, A4m, tA12);
        matmul4(tA12, A2m, tA14);
        matmul4(tA14, A1, tA15);                                 // A15
        for (int i = 0; i < 16; ++i) t_ws[T_A15 + i] = tA15[i];
        for (int o = 0; o < 2; ++o) {
            double ct = c * ((o == 0) ? th0 : th1);
            double lr = 1.0, li = ct;                            // lam^1
            for (int k = 0; k < 4; ++k) {                        // ^16
                double nr = lr*lr - li*li, ni = 2.0*lr*li; lr = nr; li = ni;
            }
            t_ws[T_LAM + (o*10 + 0)*2 + 0] = lr; t_ws[T_LAM + (o*10 + 0)*2 + 1] = li;
            for (int k = 1; k < 10; ++k) {
                double nr = lr*lr - li*li, ni = 2.0*lr*li; lr = nr; li = ni;
                t_ws[T_LAM + (o*10 + k)*2 + 0] = lr;
                t_ws[T_LAM + (o*10 + k)*2 + 1] = li;
            }
        }
    }

    float2 zc[SUB];                 // X cache, compile-time-indexed (unrolled)
    int b1 = 0, j1 = 0, len1 = 0;
    if (tid < BATCH * NS1) {
        b1 = tid / NS1; j1 = tid % NS1;
        len1 = (j1 < NS1 - 1) ? SUB : L1_LAST;
        const float* xb = X + (size_t)b1 * T_LEN * 2 + (size_t)(1 + j1 * SUB) * 2;
        double R0 = 0, I0 = 0, R1 = 0, I1 = 0;
        #pragma unroll
        for (int s = 0; s < SUB; ++s) {
            if (s < len1) {
                zc[s] = *(const float2*)(xb + 2 * s);
                step(P1, R0, I0, R1, I1, (double)zc[s].x, (double)zc[s].y);
            }
        }
        double* outp = p_ws + ((size_t)b1 * NS1 + j1) * 4;
        outp[0] = R0; outp[1] = I0; outp[2] = R1; outp[3] = I1;
    }

    grid.sync();

    // ---------------- Phase B: per-batch scan (blocks 0..63) ----------------
    if (blockIdx.x < BATCH) {
        const int b = blockIdx.x;
        const int j = threadIdx.x;
        for (int i = j; i < T_TOTAL; i += NTHR) Tl[i] = t_ws[i];

        double p00=0,p01=0,p02=0,p03=0, p10=0,p11=0,p12=0,p13=0;
        double p20=0,p21=0,p22=0,p23=0, p30=0,p31=0,p32=0,p33=0;
        if (j < NGFULL) {
            const double* p = p_ws + ((size_t)b * NS1 + 4*j) * 4;
            p00=p[0];  p01=p[1];  p02=p[2];  p03=p[3];
            p10=p[4];  p11=p[5];  p12=p[6];  p13=p[7];
            p20=p[8];  p21=p[9];  p22=p[10]; p23=p[11];
            p30=p[12]; p31=p[13]; p32=p[14]; p33=p[15];
        } else if (j == NGFULL) {
            const double* p = p_ws + ((size_t)b * NS1 + 4*j) * 4;
            p00=p[0];  p01=p[1];  p02=p[2];  p03=p[3];
            p10=p[4];  p11=p[5];  p12=p[6];  p13=p[7];
            p20=p[8];  p21=p[9];  p22=p[10]; p23=p[11];
        }
        __syncthreads();

        if (j < NGFULL) {
            const double* M48 = &Tl[T_A16 + 32];
            const double* M32 = &Tl[T_A16 + 16];
            const double* M16 = &Tl[T_A16];
            #pragma unroll
            for (int i = 0; i < 4; ++i) {
                double s = (i==0?p30:i==1?p31:i==2?p32:p33);
                s += M48[i*4+0]*p00 + M48[i*4+1]*p01 + M48[i*4+2]*p02 + M48[i*4+3]*p03;
                s += M32[i*4+0]*p10 + M32[i*4+1]*p11 + M32[i*4+2]*p12 + M32[i*4+3]*p13;
                s += M16[i*4+0]*p20 + M16[i*4+1]*p21 + M16[i*4+2]*p22 + M16[i*4+3]*p23;
                v[j*5 + i] = s;
            }
        }
        __syncthreads();

        for (int r = 0, d = 1; r < NROUNDS; ++r, d <<= 1) {
            const double* M = &Tl[T_M64 + r * 16];
            double n0 = 0, n1 = 0, n2 = 0, n3 = 0;
            bool act = (j < NGFULL) && (j >= d);
            if (act) {
                const double* q = &v[(j - d) * 5];
                double q0 = q[0], q1 = q[1], q2 = q[2], q3 = q[3];
                const double* w = &v[j * 5];
                n0 = M[0]  * q0 + M[1]  * q1 + M[2]  * q2 + M[3]  * q3 + w[0];
                n1 = M[4]  * q0 + M[5]  * q1 + M[6]  * q2 + M[7]  * q3 + w[1];
                n2 = M[8]  * q0 + M[9]  * q1 + M[10] * q2 + M[11] * q3 + w[2];
                n3 = M[12] * q0 + M[13] * q1 + M[14] * q2 + M[15] * q3 + w[3];
            }
            __syncthreads();
            if (act) { v[j*5+0] = n0; v[j*5+1] = n1; v[j*5+2] = n2; v[j*5+3] = n3; }
            __syncthreads();
        }

        if (j <= NGFULL) {
            const double* A16m = &Tl[T_A16];
            double s0 = 0, s1 = 0, s2 = 0, s3 = 0;
            if (j > 0) { s0=v[(j-1)*5+0]; s1=v[(j-1)*5+1]; s2=v[(j-1)*5+2]; s3=v[(j-1)*5+3]; }
            double* so = s_ws + ((size_t)b * NS + 4*j) * 4;
            #define STORE4(off) { so[(off)*4+0]=s0; so[(off)*4+1]=s1; so[(off)*4+2]=s2; so[(off)*4+3]=s3; }
            #define ADV(q0,q1,q2,q3) { \
                double a_ = A16m[0]*s0 + A16m[1]*s1 + A16m[2]*s2 + A16m[3]*s3 + q0; \
                double b_ = A16m[4]*s0 + A16m[5]*s1 + A16m[6]*s2 + A16m[7]*s3 + q1; \
                double c_ = A16m[8]*s0 + A16m[9]*s1 + A16m[10]*s2 + A16m[11]*s3 + q2; \
                double d_ = A16m[12]*s0 + A16m[13]*s1 + A16m[14]*s2 + A16m[15]*s3 + q3; \
                s0=a_; s1=b_; s2=c_; s3=d_; }
            if (j < NGFULL) {
                STORE4(0);
                ADV(p00,p01,p02,p03); STORE4(1);
                ADV(p10,p11,p12,p13); STORE4(2);
                ADV(p20,p21,p22,p23); STORE4(3);
            } else {
                STORE4(0);
                ADV(p00,p01,p02,p03); STORE4(1);
                ADV(p10,p11,p12,p13); STORE4(2);
                const double* A15m = &Tl[T_A15];
                double e0 = A15m[0]*s0 + A15m[1]*s1 + A15m[2]*s2 + A15m[3]*s3 + p20;
                double e1 = A15m[4]*s0 + A15m[5]*s1 + A15m[6]*s2 + A15m[7]*s3 + p21;
                double e2 = A15m[8]*s0 + A15m[9]*s1 + A15m[10]*s2 + A15m[11]*s3 + p22;
                double e3 = A15m[12]*s0 + A15m[13]*s1 + A15m[14]*s2 + A15m[15]*s3 + p23;
                send1[0]=e0; send1[1]=e1; send1[2]=e2; send1[3]=e3;
                if (b == 0) {
                    double ct0 = c * th0;   // y[0,RESET_T,0] = (1 + j*c*th0)*(e0 + j*e1)
                    double yr = e0 - ct0 * e1;
                    double yi = ct0 * e0 + e1;
                    invn[0] = 1.0 / sqrt(yr * yr + yi * yi);
                }
            }
            #undef STORE4
            #undef ADV
        }
        __syncthreads();

        // regime-2 sub starts: lam^(16m) * s_end1, m = 0..624
        for (int m = j; m < NS2; m += NTHR) {
            double q0r = 1.0, q0i = 0.0, q1r = 1.0, q1i = 0.0;
            #pragma unroll
            for (int k = 0; k < 10; ++k) {
                if (m & (1 << k)) {
                    double l0r = Tl[T_LAM + (0*10+k)*2+0], l0i = Tl[T_LAM + (0*10+k)*2+1];
                    double l1r = Tl[T_LAM + (1*10+k)*2+0], l1i = Tl[T_LAM + (1*10+k)*2+1];
                    double t0r = q0r*l0r - q0i*l0i, t0i = q0r*l0i + q0i*l0r;
                    double t1r = q1r*l1r - q1i*l1i, t1i = q1r*l1i + q1i*l1r;
                    q0r=t0r; q0i=t0i; q1r=t1r; q1i=t1i;
                }
            }
            double e0 = send1[0], e1 = send1[1], e2 = send1[2], e3 = send1[3];
            double* so = s_ws + ((size_t)b * NS + (NS1 + m)) * 4;
            so[0] = q0r * e0 - q0i * e1;
            so[1] = q0i * e0 + q0r * e1;
            so[2] = q1r * e2 - q1i * e3;
            so[3] = q1i * e2 + q1r * e3;
        }
    }

    grid.sync();

    // ---------------- Phase C: replay ----------------
    double inv = invn[0];

    // regime 1: same (b1,j1) as phase A, X from registers
    if (tid < BATCH * NS1) {
        const double* sp = s_ws + ((size_t)b1 * NS + j1) * 4;
        double R0 = sp[0], I0 = sp[1], R1 = sp[2], I1 = sp[3];
        float* yb = y_out + (size_t)b1 * T_LEN * 2;
        float* sb = ysum_out + (size_t)b1 * T_LEN;
        if (j1 == 0) {
            *(float2*)yb = make_float2(0.f, 0.f);  // y[:,0,:] = 0
            sb[0] = 0.f; sb[1] = 0.f;
        }
        int t0 = 1 + j1 * SUB;
        #pragma unroll
        for (int s = 0; s < SUB; ++s) {
            if (s < len1) {
                step(P1, R0, I0, R1, I1, (double)zc[s].x, (double)zc[s].y);
                int t = t0 + s;
                *(float2*)(yb + (size_t)t * 2) =
                    make_float2((float)(R0 * inv), (float)(R1 * inv));
                sb[t + 1] = (float)((R0 + R1) * inv);
            }
        }
    }

    // regime 2: items r = 0..BATCH*NS2-1, balanced across threads
    {
        int r = -1;
        const int spill = BATCH * NS2 - (NTOT - BATCH * NS1);   // items not covered by tail threads
        if (tid >= BATCH * NS1) r = tid - BATCH * NS1;          // tail threads: 0..11071
        else if (tid < spill)   r = (NTOT - BATCH * NS1) + tid; // low threads: 11072..39999
        if (r >= 0) {
            Params P2 = make_params(c, th0, th1, 0.0, 0.0);
            int b = r / NS2, m = r % NS2;
            const double* sp = s_ws + ((size_t)b * NS + (NS1 + m)) * 4;
            double R0 = sp[0], I0 = sp[1], R1 = sp[2], I1 = sp[3];
            float* yb = y_out + (size_t)b * T_LEN * 2;
            float* sb = ysum_out + (size_t)b * T_LEN;
            int t0 = RESET_T + m * SUB;
            #pragma unroll
            for (int s = 0; s < SUB; ++s) {
                int t = t0 + s;
                step(P2, R0, I0, R1, I1, 0.0, 0.0);
                *(float2*)(yb + (size_t)t * 2) =
                    make_float2((float)(R0 * inv), (float)(R1 * inv));
                if (t + 1 < T_LEN) sb[t + 1] = (float)((R0 + R1) * inv);
            }
        }
    }
}

extern "C" void kernel_launch(void* const* d_in, const int* in_sizes, int n_in,
                              void* d_out, int out_size, void* d_ws, size_t ws_size,
                              hipStream_t stream) {
    const float* X     = (const float*)d_in[0];
    const float* tau   = (const float*)d_in[1];
    const float* omega = (const float*)d_in[2];
    const float* a0    = (const float*)d_in[3];
    const float* b0    = (const float*)d_in[4];
    float* out = (float*)d_out;

    // Scratch in d_ws (~9 MB of 256 MiB); fully rewritten every call.
    double* p_ws = (double*)d_ws;                        // [BATCH][NS1][4]
    double* s_ws = p_ws + (size_t)NS1 * BATCH * 4;       // [BATCH][NS][4]
    double* invn = s_ws + (size_t)NS * BATCH * 4;
    double* t_ws = invn + 8;                             // T_TOTAL doubles

    float* b_outp  = out + B_OFF;
    float* a_outp  = out + A_OFF;
    float* y_outp  = out;
    float* ys_outp = out + YS_OFF;

    void* args[] = { (void*)&X, (void*)&tau, (void*)&omega, (void*)&a0, (void*)&b0,
                     (void*)&p_ws, (void*)&t_ws, (void*)&s_ws, (void*)&invn,
                     (void*)&b_outp, (void*)&a_outp, (void*)&y_outp, (void*)&ys_outp };
    hipLaunchCooperativeKernel((const void*)fused_all, dim3(NBLK), dim3(NTHR),
                               args, 0, stream);
}

// Round 12
// 41.330 us; speedup vs baseline: 3.1065x; 3.1065x over previous
//
#include <hip/hip_runtime.h>
#include <math.h>

#define T_LEN   40000
#define BATCH   64
#define RESET_T 30000
#define SUB     16
// regime 1: steps 1..29999 -> 1875 sub-chunks of 16 (1874 full, last = 15)
// regime 2: steps 30000..39999 -> 625 sub-chunks of 16 (all full)
#define NS1     1875
#define L1_LAST 15
#define NS2     625
#define NS      (NS1 + NS2)
// scan groups: 4 subs each (64 steps); groups 0..467 full, group 468 = 3 subs (47 steps)
#define NGFULL  468
#define NROUNDS 9
#define PI_D    3.14159265358979323846

#define NB1     8    // ceil(NS1/256): k1 blocks per batch (last block: 83 subs)
#define NB3     10   // ceil(NS /256): k3 blocks per batch (last block: 196 subs)

// uniform table in d_ws (doubles):
#define T_A16   0      // 3 mats: A^16, A^32, A^48
#define T_M64   48     // 9 mats: (A^64)^(2^r), r=0..8
#define T_A15   192    // 1 mat: A^15
#define T_LAM   208    // 2 osc * 10 * (re,im) = 40
#define T_TOTAL 248

// d_out layout in FLOATS (complex outputs validated as real part only):
#define Y_SIZE  ((size_t)BATCH * T_LEN * 2)
#define B_OFF   (Y_SIZE)
#define A_OFF   (B_OFF + T_LEN)
#define YS_OFF  (A_OFF + T_LEN)

struct Params { double alpha, beta, g0, g1, delta, k; };

__device__ __forceinline__ Params make_params(double c, double th0, double th1,
                                              double a, double b) {
    double inva = 1.0 / (1.0 + a);
    double bb   = b / (1.0 + b);
    Params p;
    p.alpha = 1.0 + c * (inva - 1.0);
    p.beta  = 1.0 + c * (inva - 1.0 + bb);
    p.g0    = c * inva * th0;
    p.g1    = c * inva * th1;
    p.delta = c * bb;
    p.k     = c * bb;
    return p;
}

__device__ __forceinline__ void get_consts(const float* tau, const float* omega,
                                           double& c, double& th0, double& th1) {
    double tv = (double)tau[0];
    c   = 0.1 / tv;
    th0 = 2.0 * PI_D * tv * (double)omega[0];
    th1 = 2.0 * PI_D * tv * (double)omega[1];
}

__device__ __forceinline__ void step(const Params& P, double& R0, double& I0,
                                     double& R1, double& I1, double z0, double z1) {
    double nR0 = P.alpha * R0 - P.g0 * I0 - P.delta * R1 + P.k * z0;
    double nI0 = P.g0 * R0 + P.beta * I0;
    double nR1 = P.alpha * R1 - P.g1 * I1 - P.delta * R0 + P.k * z1;
    double nI1 = P.g1 * R1 + P.beta * I1;
    R0 = nR0; I0 = nI0; R1 = nR1; I1 = nI1;
}

__device__ __forceinline__ void matmul4(const double* A, const double* B, double* C) {
    for (int i = 0; i < 4; ++i)
        for (int jj = 0; jj < 4; ++jj) {
            double s = 0.0;
            for (int l = 0; l < 4; ++l) s += A[i * 4 + l] * B[l * 4 + jj];
            C[i * 4 + jj] = s;
        }
}

__device__ void build_A(const Params& P, double* A) {
    A[0]  = P.alpha; A[1]  = -P.g0;  A[2]  = -P.delta; A[3]  = 0.0;
    A[4]  = P.g0;    A[5]  = P.beta; A[6]  = 0.0;      A[7]  = 0.0;
    A[8]  = -P.delta;A[9]  = 0.0;    A[10] = P.alpha;  A[11] = -P.g1;
    A[12] = 0.0;     A[13] = 0.0;    A[14] = P.g1;     A[15] = P.beta;
}

// ---------------- K1: LDS-staged 16-step partials + b/a fill + table build ----------------
// block = 256 consecutive subs of one batch. X staged coalesced via LDS.
__global__ __launch_bounds__(256) void k1_partial(const float* __restrict__ X,
        const float* tau, const float* omega, const float* a0, const float* b0,
        double* __restrict__ p_out, float* __restrict__ b_out, float* __restrict__ a_out,
        double* __restrict__ t_ws) {
    __shared__ float2 xs[256 * 17];   // row pad 16->17 breaks bank alignment
    const int bx = blockIdx.x;
    const int b  = bx / NB1, blk = bx % NB1;
    const int j0 = blk * 256;
    const int nsub = (NS1 - j0 < 256) ? (NS1 - j0) : 256;
    const int gtid = bx * 256 + threadIdx.x;

    if (gtid < T_LEN) {
        b_out[gtid] = (gtid < RESET_T) ? b0[0] : 0.0f;
        a_out[gtid] = (gtid < RESET_T) ? a0[0] : 0.0f;
    }

    double c, th0, th1; get_consts(tau, omega, c, th0, th1);
    Params P = make_params(c, th0, th1, (double)a0[0], (double)b0[0]);

    if (gtid == 0) {
        double A1[16], A2m[16], A4m[16], A8m[16], tA12[16], tA14[16], tA15[16];
        build_A(P, A1);
        matmul4(A1, A1, A2m);
        matmul4(A2m, A2m, A4m);
        matmul4(A4m, A4m, A8m);
        matmul4(A8m, A8m, &t_ws[T_A16]);                         // A16
        matmul4(&t_ws[T_A16], &t_ws[T_A16], &t_ws[T_A16+16]);    // A32
        matmul4(&t_ws[T_A16+16], &t_ws[T_A16], &t_ws[T_A16+32]); // A48
        matmul4(&t_ws[T_A16+32], &t_ws[T_A16], &t_ws[T_M64]);    // A64
        for (int r = 1; r < NROUNDS; ++r)
            matmul4(&t_ws[T_M64 + (r-1)*16], &t_ws[T_M64 + (r-1)*16],
                    &t_ws[T_M64 + r*16]);
        matmul4(A8m, A4m, tA12);
        matmul4(tA12, A2m, tA14);
        matmul4(tA14, A1, tA15);                                 // A15
        for (int i = 0; i < 16; ++i) t_ws[T_A15 + i] = tA15[i];
        for (int o = 0; o < 2; ++o) {
            double ct = c * ((o == 0) ? th0 : th1);
            double lr = 1.0, li = ct;                            // lam^1
            for (int k = 0; k < 4; ++k) {                        // ^16
                double nr = lr*lr - li*li, ni = 2.0*lr*li; lr = nr; li = ni;
            }
            t_ws[T_LAM + (o*10 + 0)*2 + 0] = lr; t_ws[T_LAM + (o*10 + 0)*2 + 1] = li;
            for (int k = 1; k < 10; ++k) {
                double nr = lr*lr - li*li, ni = 2.0*lr*li; lr = nr; li = ni;
                t_ws[T_LAM + (o*10 + k)*2 + 0] = lr;
                t_ws[T_LAM + (o*10 + k)*2 + 1] = li;
            }
        }
    }

    // coalesced X stage: nsub*16 float2 starting at t = 1 + j0*16
    const int nld = nsub * 16;
    const float* xg = X + ((size_t)b * T_LEN + 1 + (size_t)j0 * SUB) * 2;
    for (int i = threadIdx.x; i < nld; i += 256)
        xs[(i >> 4) * 17 + (i & 15)] = *(const float2*)(xg + 2 * i);
    __syncthreads();

    const int tid = threadIdx.x;
    if (tid < nsub) {
        int j = j0 + tid;
        int len = (j < NS1 - 1) ? SUB : L1_LAST;
        double R0 = 0, I0 = 0, R1 = 0, I1 = 0;
        #pragma unroll
        for (int s = 0; s < SUB; ++s) {
            if (s < len) {
                float2 z = xs[tid * 17 + s];
                step(P, R0, I0, R1, I1, (double)z.x, (double)z.y);
            }
        }
        double* outp = p_out + ((size_t)b * NS1 + j) * 4;
        outp[0] = R0; outp[1] = I0; outp[2] = R1; outp[3] = I1;
    }
}

// ---------------- K2: combine(4x16->64) + Kogge-Stone + expand(64->16) ----------------
__global__ __launch_bounds__(512) void k2_scan_par(const float* tau, const float* omega,
        const float* a0, const float* b0, const double* __restrict__ p_in,
        const double* __restrict__ t_ws,
        double* __restrict__ s_out, double* __restrict__ invn) {
    __shared__ double v[NGFULL * 5];      // stride 5: bank-conflict-free
    __shared__ double Tl[T_TOTAL];
    __shared__ double send1[4];
    int b = blockIdx.x;
    int j = threadIdx.x;

    for (int i = j; i < T_TOTAL; i += 512) Tl[i] = t_ws[i];

    double c, th0, th1; get_consts(tau, omega, c, th0, th1);

    double p00=0,p01=0,p02=0,p03=0, p10=0,p11=0,p12=0,p13=0;
    double p20=0,p21=0,p22=0,p23=0, p30=0,p31=0,p32=0,p33=0;
    if (j < NGFULL) {
        const double* p = p_in + ((size_t)b * NS1 + 4*j) * 4;
        p00=p[0];  p01=p[1];  p02=p[2];  p03=p[3];
        p10=p[4];  p11=p[5];  p12=p[6];  p13=p[7];
        p20=p[8];  p21=p[9];  p22=p[10]; p23=p[11];
        p30=p[12]; p31=p[13]; p32=p[14]; p33=p[15];
    } else if (j == NGFULL) {
        const double* p = p_in + ((size_t)b * NS1 + 4*j) * 4;
        p00=p[0];  p01=p[1];  p02=p[2];  p03=p[3];
        p10=p[4];  p11=p[5];  p12=p[6];  p13=p[7];
        p20=p[8];  p21=p[9];  p22=p[10]; p23=p[11];
    }
    __syncthreads();

    if (j < NGFULL) {
        const double* M48 = &Tl[T_A16 + 32];
        const double* M32 = &Tl[T_A16 + 16];
        const double* M16 = &Tl[T_A16];
        #pragma unroll
        for (int i = 0; i < 4; ++i) {
            double s = (i==0?p30:i==1?p31:i==2?p32:p33);
            s += M48[i*4+0]*p00 + M48[i*4+1]*p01 + M48[i*4+2]*p02 + M48[i*4+3]*p03;
            s += M32[i*4+0]*p10 + M32[i*4+1]*p11 + M32[i*4+2]*p12 + M32[i*4+3]*p13;
            s += M16[i*4+0]*p20 + M16[i*4+1]*p21 + M16[i*4+2]*p22 + M16[i*4+3]*p23;
            v[j*5 + i] = s;
        }
    }
    __syncthreads();

    for (int r = 0, d = 1; r < NROUNDS; ++r, d <<= 1) {
        const double* M = &Tl[T_M64 + r * 16];
        double n0 = 0, n1 = 0, n2 = 0, n3 = 0;
        bool act = (j < NGFULL) && (j >= d);
        if (act) {
            const double* q = &v[(j - d) * 5];
            double q0 = q[0], q1 = q[1], q2 = q[2], q3 = q[3];
            const double* w = &v[j * 5];
            n0 = M[0]  * q0 + M[1]  * q1 + M[2]  * q2 + M[3]  * q3 + w[0];
            n1 = M[4]  * q0 + M[5]  * q1 + M[6]  * q2 + M[7]  * q3 + w[1];
            n2 = M[8]  * q0 + M[9]  * q1 + M[10] * q2 + M[11] * q3 + w[2];
            n3 = M[12] * q0 + M[13] * q1 + M[14] * q2 + M[15] * q3 + w[3];
        }
        __syncthreads();
        if (act) { v[j*5+0] = n0; v[j*5+1] = n1; v[j*5+2] = n2; v[j*5+3] = n3; }
        __syncthreads();
    }

    if (j <= NGFULL) {
        const double* A16m = &Tl[T_A16];
        double s0 = 0, s1 = 0, s2 = 0, s3 = 0;
        if (j > 0) { s0=v[(j-1)*5+0]; s1=v[(j-1)*5+1]; s2=v[(j-1)*5+2]; s3=v[(j-1)*5+3]; }
        double* so = s_out + ((size_t)b * NS + 4*j) * 4;
        #define STORE4(off) { so[(off)*4+0]=s0; so[(off)*4+1]=s1; so[(off)*4+2]=s2; so[(off)*4+3]=s3; }
        #define ADV(q0,q1,q2,q3) { \
            double a_ = A16m[0]*s0 + A16m[1]*s1 + A16m[2]*s2 + A16m[3]*s3 + q0; \
            double b_ = A16m[4]*s0 + A16m[5]*s1 + A16m[6]*s2 + A16m[7]*s3 + q1; \
            double c_ = A16m[8]*s0 + A16m[9]*s1 + A16m[10]*s2 + A16m[11]*s3 + q2; \
            double d_ = A16m[12]*s0 + A16m[13]*s1 + A16m[14]*s2 + A16m[15]*s3 + q3; \
            s0=a_; s1=b_; s2=c_; s3=d_; }
        if (j < NGFULL) {
            STORE4(0);
            ADV(p00,p01,p02,p03); STORE4(1);
            ADV(p10,p11,p12,p13); STORE4(2);
            ADV(p20,p21,p22,p23); STORE4(3);
        } else {
            STORE4(0);
            ADV(p00,p01,p02,p03); STORE4(1);
            ADV(p10,p11,p12,p13); STORE4(2);
            const double* A15m = &Tl[T_A15];
            double e0 = A15m[0]*s0 + A15m[1]*s1 + A15m[2]*s2 + A15m[3]*s3 + p20;
            double e1 = A15m[4]*s0 + A15m[5]*s1 + A15m[6]*s2 + A15m[7]*s3 + p21;
            double e2 = A15m[8]*s0 + A15m[9]*s1 + A15m[10]*s2 + A15m[11]*s3 + p22;
            double e3 = A15m[12]*s0 + A15m[13]*s1 + A15m[14]*s2 + A15m[15]*s3 + p23;
            send1[0]=e0; send1[1]=e1; send1[2]=e2; send1[3]=e3;
            if (b == 0) {
                double ct0 = c * th0;   // y[0,RESET_T,0] = (1 + j*c*th0)*(e0 + j*e1)
                double yr = e0 - ct0 * e1;
                double yi = ct0 * e0 + e1;
                invn[0] = 1.0 / sqrt(yr * yr + yi * yi);
            }
        }
        #undef STORE4
        #undef ADV
    }
    __syncthreads();

    // regime-2 sub starts: lam^(16m) * s_end1, m = 0..624
    for (int m = j; m < NS2; m += 512) {
        double q0r = 1.0, q0i = 0.0, q1r = 1.0, q1i = 0.0;
        #pragma unroll
        for (int k = 0; k < 10; ++k) {
            if (m & (1 << k)) {
                double l0r = Tl[T_LAM + (0*10+k)*2+0], l0i = Tl[T_LAM + (0*10+k)*2+1];
                double l1r = Tl[T_LAM + (1*10+k)*2+0], l1i = Tl[T_LAM + (1*10+k)*2+1];
                double t0r = q0r*l0r - q0i*l0i, t0i = q0r*l0i + q0i*l0r;
                double t1r = q1r*l1r - q1i*l1i, t1i = q1r*l1i + q1i*l1r;
                q0r=t0r; q0i=t0i; q1r=t1r; q1i=t1i;
            }
        }
        double e0 = send1[0], e1 = send1[1], e2 = send1[2], e3 = send1[3];
        double* so = s_out + ((size_t)b * NS + (NS1 + m)) * 4;
        so[0] = q0r * e0 - q0i * e1;
        so[1] = q0i * e0 + q0r * e1;
        so[2] = q1r * e2 - q1i * e3;
        so[3] = q1i * e2 + q1r * e3;
    }
}

// ---------------- K3: LDS-staged replay — coalesced X in, coalesced y/ysum out ----------------
// block = 256 consecutive subs of one batch; X slots are overwritten in place by y.
__global__ __launch_bounds__(256) void k3_replay(const float* __restrict__ X,
        const float* tau, const float* omega, const float* a0, const float* b0,
        const double* __restrict__ s_in, const double* __restrict__ invn,
        float* __restrict__ y_out, float* __restrict__ ysum_out) {
    __shared__ float2 ys[256 * 17];   // X staged in; y written over consumed slots
    const int bx = blockIdx.x;
    const int b  = bx / NB3, blk = bx % NB3;
    const int j0 = blk * 256;
    const int nsub = (NS - j0 < 256) ? (NS - j0) : 256;
    int r1c = NS1 - j0; if (r1c < 0) r1c = 0; if (r1c > nsub) r1c = nsub;

    // coalesced X stage for regime-1 rows only
    const int nld = r1c * 16;
    const float* xg = X + ((size_t)b * T_LEN + 1 + (size_t)j0 * SUB) * 2;
    for (int i = threadIdx.x; i < nld; i += 256)
        ys[(i >> 4) * 17 + (i & 15)] = *(const float2*)(xg + 2 * i);
    __syncthreads();

    double c, th0, th1; get_consts(tau, omega, c, th0, th1);
    const double inv = invn[0];
    const int tid = threadIdx.x;

    if (tid < nsub) {
        int j = j0 + tid;
        const double* sp = s_in + ((size_t)b * NS + j) * 4;
        double R0 = sp[0], I0 = sp[1], R1 = sp[2], I1 = sp[3];
        if (j < NS1) {
            Params P = make_params(c, th0, th1, (double)a0[0], (double)b0[0]);
            int len = (j < NS1 - 1) ? SUB : L1_LAST;
            #pragma unroll
            for (int s = 0; s < SUB; ++s) {
                if (s < len) {
                    float2 z = ys[tid * 17 + s];
                    step(P, R0, I0, R1, I1, (double)z.x, (double)z.y);
                    ys[tid * 17 + s] = make_float2((float)(R0 * inv), (float)(R1 * inv));
                }
            }
        } else {
            Params P = make_params(c, th0, th1, 0.0, 0.0);
            #pragma unroll
            for (int s = 0; s < SUB; ++s) {
                step(P, R0, I0, R1, I1, 0.0, 0.0);
                ys[tid * 17 + s] = make_float2((float)(R0 * inv), (float)(R1 * inv));
            }
        }
    }
    __syncthreads();

    // coalesced store-out: consecutive i -> consecutive t (within each regime span)
    float* yb = y_out + (size_t)b * T_LEN * 2;
    float* sb = ysum_out + (size_t)b * T_LEN;
    if (blk == 0 && threadIdx.x == 0) {
        yb[0] = 0.f; yb[1] = 0.f;   // y[:,0,:] = 0
        sb[0] = 0.f; sb[1] = 0.f;   // ysum[0] = 0; ysum[1] = sum(y[0]) = 0
    }
    const int ntot = nsub * 16;
    for (int i = threadIdx.x; i < ntot; i += 256) {
        int jj = i >> 4, s = i & 15;
        int j = j0 + jj;
        int t;
        if (j < NS1) {
            if (j == NS1 - 1 && s >= L1_LAST) continue;   // 15-step tail sub
            t = 1 + j * SUB + s;
        } else {
            t = RESET_T + (j - NS1) * SUB + s;
        }
        float2 v2 = ys[jj * 17 + s];
        *(float2*)(yb + (size_t)t * 2) = v2;
        if (t + 1 < T_LEN) sb[t + 1] = v2.x + v2.y;
    }
}

extern "C" void kernel_launch(void* const* d_in, const int* in_sizes, int n_in,
                              void* d_out, int out_size, void* d_ws, size_t ws_size,
                              hipStream_t stream) {
    const float* X     = (const float*)d_in[0];
    const float* tau   = (const float*)d_in[1];
    const float* omega = (const float*)d_in[2];
    const float* a0    = (const float*)d_in[3];
    const float* b0    = (const float*)d_in[4];
    float* out = (float*)d_out;

    // Scratch in d_ws (~9 MB of 256 MiB); fully rewritten every call.
    double* p_ws = (double*)d_ws;                        // [BATCH][NS1][4]
    double* s_ws = p_ws + (size_t)NS1 * BATCH * 4;       // [BATCH][NS][4]
    double* invn = s_ws + (size_t)NS * BATCH * 4;
    double* t_ws = invn + 8;                             // T_TOTAL doubles

    k1_partial<<<BATCH * NB1, 256, 0, stream>>>(X, tau, omega, a0, b0, p_ws,
                                                out + B_OFF, out + A_OFF, t_ws);
    k2_scan_par<<<BATCH, 512, 0, stream>>>(tau, omega, a0, b0, p_ws, t_ws, s_ws, invn);
    k3_replay<<<BATCH * NB3, 256, 0, stream>>>(X, tau, omega, a0, b0, s_ws, invn,
                                               out, out + YS_OFF);
}

// Round 13
// 32.559 us; speedup vs baseline: 3.9434x; 1.2694x over previous
//
#include <hip/hip_runtime.h>
#include <math.h>

#define T_LEN   40000
#define BATCH   64
#define RESET_T 30000
#define SUB     16
// regime 1: steps 1..29999 -> 1875 sub-chunks of 16 (1874 full, last = 15)
// regime 2: steps 30000..39999 -> 625 sub-chunks of 16 (all full)
#define NS1     1875
#define L1_LAST 15
#define NS2     625
#define NS      (NS1 + NS2)
// scan groups: 4 subs each (64 steps); groups 0..467 full, group 468 = 3 subs (47 steps)
#define NGFULL  468
#define NROUNDS 9
#define PI_D    3.14159265358979323846

#define NB1     8    // ceil(NS1/256): k1 blocks per batch
#define NB3     10   // ceil(NS /256): k3 blocks per batch

// uniform table (doubles at start of d_ws):
#define T_A16   0      // 3 mats: A^16, A^32, A^48
#define T_M64   48     // 9 mats: (A^64)^(2^r), r=0..8
#define T_A15   192    // 1 mat: A^15
#define T_LAM   208    // 2 osc * 10 * (re,im) = 40   (lam^(16*2^k))
#define T_TOTAL 248

// d_out layout in FLOATS (complex outputs validated as real part only):
#define Y_SIZE  ((size_t)BATCH * T_LEN * 2)
#define B_OFF   (Y_SIZE)
#define A_OFF   (B_OFF + T_LEN)
#define YS_OFF  (A_OFF + T_LEN)

// 16-byte vector with only 8-byte alignment requirement (regime-1 y stores land
// at odd-t*8B offsets; AMD global ops only need dword alignment).
typedef struct __attribute__((aligned(8))) { float x, y, z, w; } f4a8;

struct Params { double alpha, beta, g0, g1, delta, k; };

__device__ __forceinline__ Params make_params(double c, double th0, double th1,
                                              double a, double b) {
    double inva = 1.0 / (1.0 + a);
    double bb   = b / (1.0 + b);
    Params p;
    p.alpha = 1.0 + c * (inva - 1.0);
    p.beta  = 1.0 + c * (inva - 1.0 + bb);
    p.g0    = c * inva * th0;
    p.g1    = c * inva * th1;
    p.delta = c * bb;
    p.k     = c * bb;
    return p;
}

__device__ __forceinline__ void get_consts(const float* tau, const float* omega,
                                           double& c, double& th0, double& th1) {
    double tv = (double)tau[0];
    c   = 0.1 / tv;
    th0 = 2.0 * PI_D * tv * (double)omega[0];
    th1 = 2.0 * PI_D * tv * (double)omega[1];
}

__device__ __forceinline__ void step(const Params& P, double& R0, double& I0,
                                     double& R1, double& I1, double z0, double z1) {
    double nR0 = P.alpha * R0 - P.g0 * I0 - P.delta * R1 + P.k * z0;
    double nI0 = P.g0 * R0 + P.beta * I0;
    double nR1 = P.alpha * R1 - P.g1 * I1 - P.delta * R0 + P.k * z1;
    double nI1 = P.g1 * R1 + P.beta * I1;
    R0 = nR0; I0 = nI0; R1 = nR1; I1 = nI1;
}

__device__ __forceinline__ void matmul4(const double* A, const double* B, double* C) {
    for (int i = 0; i < 4; ++i)
        for (int jj = 0; jj < 4; ++jj) {
            double s = 0.0;
            for (int l = 0; l < 4; ++l) s += A[i * 4 + l] * B[l * 4 + jj];
            C[i * 4 + jj] = s;
        }
}

__device__ void build_A(const Params& P, double* A) {
    A[0]  = P.alpha; A[1]  = -P.g0;  A[2]  = -P.delta; A[3]  = 0.0;
    A[4]  = P.g0;    A[5]  = P.beta; A[6]  = 0.0;      A[7]  = 0.0;
    A[8]  = -P.delta;A[9]  = 0.0;    A[10] = P.alpha;  A[11] = -P.g1;
    A[12] = 0.0;     A[13] = 0.0;    A[14] = P.g1;     A[15] = P.beta;
}

// ---------------- K1: LDS-staged 16-step partials + b/a fill + table build ----------------
__global__ __launch_bounds__(256) void k1_partial(const float* __restrict__ X,
        const float* tau, const float* omega, const float* a0, const float* b0,
        float* __restrict__ p_out, float* __restrict__ b_out, float* __restrict__ a_out,
        double* __restrict__ t_ws) {
    __shared__ float2 xs[256 * 17];
    const int bx = blockIdx.x;
    const int b  = bx / NB1, blk = bx % NB1;
    const int j0 = blk * 256;
    const int nsub = (NS1 - j0 < 256) ? (NS1 - j0) : 256;
    const int gtid = bx * 256 + threadIdx.x;

    if (gtid < T_LEN) {
        b_out[gtid] = (gtid < RESET_T) ? b0[0] : 0.0f;
        a_out[gtid] = (gtid < RESET_T) ? a0[0] : 0.0f;
    }

    double c, th0, th1; get_consts(tau, omega, c, th0, th1);
    Params P = make_params(c, th0, th1, (double)a0[0], (double)b0[0]);

    if (gtid == 0) {
        double A1[16], A2m[16], A4m[16], A8m[16], tA12[16], tA14[16], tA15[16];
        build_A(P, A1);
        matmul4(A1, A1, A2m);
        matmul4(A2m, A2m, A4m);
        matmul4(A4m, A4m, A8m);
        matmul4(A8m, A8m, &t_ws[T_A16]);                         // A16
        matmul4(&t_ws[T_A16], &t_ws[T_A16], &t_ws[T_A16+16]);    // A32
        matmul4(&t_ws[T_A16+16], &t_ws[T_A16], &t_ws[T_A16+32]); // A48
        matmul4(&t_ws[T_A16+32], &t_ws[T_A16], &t_ws[T_M64]);    // A64
        for (int r = 1; r < NROUNDS; ++r)
            matmul4(&t_ws[T_M64 + (r-1)*16], &t_ws[T_M64 + (r-1)*16],
                    &t_ws[T_M64 + r*16]);
        matmul4(A8m, A4m, tA12);
        matmul4(tA12, A2m, tA14);
        matmul4(tA14, A1, tA15);                                 // A15
        for (int i = 0; i < 16; ++i) t_ws[T_A15 + i] = tA15[i];
        for (int o = 0; o < 2; ++o) {
            double ct = c * ((o == 0) ? th0 : th1);
            double lr = 1.0, li = ct;                            // lam^1
            for (int k = 0; k < 4; ++k) {                        // ^16
                double nr = lr*lr - li*li, ni = 2.0*lr*li; lr = nr; li = ni;
            }
            t_ws[T_LAM + (o*10 + 0)*2 + 0] = lr; t_ws[T_LAM + (o*10 + 0)*2 + 1] = li;
            for (int k = 1; k < 10; ++k) {
                double nr = lr*lr - li*li, ni = 2.0*lr*li; lr = nr; li = ni;
                t_ws[T_LAM + (o*10 + k)*2 + 0] = lr;
                t_ws[T_LAM + (o*10 + k)*2 + 1] = li;
            }
        }
    }

    // coalesced X stage, float4 granularity (two float2 per load, same LDS row)
    const int nld2 = nsub * 8;
    const float* xg = X + ((size_t)b * T_LEN + 1 + (size_t)j0 * SUB) * 2;
    for (int i2 = threadIdx.x; i2 < nld2; i2 += 256) {
        f4a8 v = *(const f4a8*)(xg + 4 * i2);
        int i = 2 * i2;
        *(f4a8*)&xs[(i >> 4) * 17 + (i & 15)] = v;
    }
    __syncthreads();

    const int tid = threadIdx.x;
    if (tid < nsub) {
        int j = j0 + tid;
        int len = (j < NS1 - 1) ? SUB : L1_LAST;
        double R0 = 0, I0 = 0, R1 = 0, I1 = 0;
        #pragma unroll
        for (int s = 0; s < SUB; ++s) {
            if (s < len) {
                float2 z = xs[tid * 17 + s];
                step(P, R0, I0, R1, I1, (double)z.x, (double)z.y);
            }
        }
        *(float4*)(p_out + ((size_t)b * NS1 + j) * 4) =
            make_float4((float)R0, (float)I0, (float)R1, (float)I1);
    }
}

// ---------------- K2: combine + Kogge-Stone + regime-1 expand; send1 out ----------------
__global__ __launch_bounds__(512) void k2_scan_par(const float* tau, const float* omega,
        const float* a0, const float* b0, const float* __restrict__ p_in,
        const double* __restrict__ t_ws,
        float* __restrict__ s_out, double* __restrict__ send1_ws,
        double* __restrict__ invn) {
    __shared__ double v[NGFULL * 5];      // stride 5: bank-conflict-free
    __shared__ double Tl[T_TOTAL];
    int b = blockIdx.x;
    int j = threadIdx.x;

    for (int i = j; i < T_TOTAL; i += 512) Tl[i] = t_ws[i];

    double c, th0, th1; get_consts(tau, omega, c, th0, th1);

    double p00=0,p01=0,p02=0,p03=0, p10=0,p11=0,p12=0,p13=0;
    double p20=0,p21=0,p22=0,p23=0, p30=0,p31=0,p32=0,p33=0;
    if (j <= NGFULL) {
        const float4* p = (const float4*)(p_in + ((size_t)b * NS1 + 4*j) * 4);
        float4 q0 = p[0], q1 = p[1], q2 = p[2];
        p00=q0.x; p01=q0.y; p02=q0.z; p03=q0.w;
        p10=q1.x; p11=q1.y; p12=q1.z; p13=q1.w;
        p20=q2.x; p21=q2.y; p22=q2.z; p23=q2.w;
        if (j < NGFULL) {
            float4 q3 = p[3];
            p30=q3.x; p31=q3.y; p32=q3.z; p33=q3.w;
        }
    }
    __syncthreads();

    if (j < NGFULL) {
        const double* M48 = &Tl[T_A16 + 32];
        const double* M32 = &Tl[T_A16 + 16];
        const double* M16 = &Tl[T_A16];
        #pragma unroll
        for (int i = 0; i < 4; ++i) {
            double s = (i==0?p30:i==1?p31:i==2?p32:p33);
            s += M48[i*4+0]*p00 + M48[i*4+1]*p01 + M48[i*4+2]*p02 + M48[i*4+3]*p03;
            s += M32[i*4+0]*p10 + M32[i*4+1]*p11 + M32[i*4+2]*p12 + M32[i*4+3]*p13;
            s += M16[i*4+0]*p20 + M16[i*4+1]*p21 + M16[i*4+2]*p22 + M16[i*4+3]*p23;
            v[j*5 + i] = s;
        }
    }
    __syncthreads();

    for (int r = 0, d = 1; r < NROUNDS; ++r, d <<= 1) {
        const double* M = &Tl[T_M64 + r * 16];
        double n0 = 0, n1 = 0, n2 = 0, n3 = 0;
        bool act = (j < NGFULL) && (j >= d);
        if (act) {
            const double* q = &v[(j - d) * 5];
            double q0 = q[0], q1 = q[1], q2 = q[2], q3 = q[3];
            const double* w = &v[j * 5];
            n0 = M[0]  * q0 + M[1]  * q1 + M[2]  * q2 + M[3]  * q3 + w[0];
            n1 = M[4]  * q0 + M[5]  * q1 + M[6]  * q2 + M[7]  * q3 + w[1];
            n2 = M[8]  * q0 + M[9]  * q1 + M[10] * q2 + M[11] * q3 + w[2];
            n3 = M[12] * q0 + M[13] * q1 + M[14] * q2 + M[15] * q3 + w[3];
        }
        __syncthreads();
        if (act) { v[j*5+0] = n0; v[j*5+1] = n1; v[j*5+2] = n2; v[j*5+3] = n3; }
        __syncthreads();
    }

    if (j <= NGFULL) {
        const double* A16m = &Tl[T_A16];
        double s0 = 0, s1 = 0, s2 = 0, s3 = 0;
        if (j > 0) { s0=v[(j-1)*5+0]; s1=v[(j-1)*5+1]; s2=v[(j-1)*5+2]; s3=v[(j-1)*5+3]; }
        float4* so = (float4*)(s_out + ((size_t)b * NS1 + 4*j) * 4);
        #define STORE4(off) { so[off] = make_float4((float)s0,(float)s1,(float)s2,(float)s3); }
        #define ADV(q0,q1,q2,q3) { \
            double a_ = A16m[0]*s0 + A16m[1]*s1 + A16m[2]*s2 + A16m[3]*s3 + q0; \
            double b_ = A16m[4]*s0 + A16m[5]*s1 + A16m[6]*s2 + A16m[7]*s3 + q1; \
            double c_ = A16m[8]*s0 + A16m[9]*s1 + A16m[10]*s2 + A16m[11]*s3 + q2; \
            double d_ = A16m[12]*s0 + A16m[13]*s1 + A16m[14]*s2 + A16m[15]*s3 + q3; \
            s0=a_; s1=b_; s2=c_; s3=d_; }
        if (j < NGFULL) {
            STORE4(0);
            ADV(p00,p01,p02,p03); STORE4(1);
            ADV(p10,p11,p12,p13); STORE4(2);
            ADV(p20,p21,p22,p23); STORE4(3);
        } else {
            STORE4(0);
            ADV(p00,p01,p02,p03); STORE4(1);
            ADV(p10,p11,p12,p13); STORE4(2);
            const double* A15m = &Tl[T_A15];
            double e0 = A15m[0]*s0 + A15m[1]*s1 + A15m[2]*s2 + A15m[3]*s3 + p20;
            double e1 = A15m[4]*s0 + A15m[5]*s1 + A15m[6]*s2 + A15m[7]*s3 + p21;
            double e2 = A15m[8]*s0 + A15m[9]*s1 + A15m[10]*s2 + A15m[11]*s3 + p22;
            double e3 = A15m[12]*s0 + A15m[13]*s1 + A15m[14]*s2 + A15m[15]*s3 + p23;
            send1_ws[b*4+0]=e0; send1_ws[b*4+1]=e1;
            send1_ws[b*4+2]=e2; send1_ws[b*4+3]=e3;
            if (b == 0) {
                double ct0 = c * th0;   // y[0,RESET_T,0] = (1 + j*c*th0)*(e0 + j*e1)
                double yr = e0 - ct0 * e1;
                double yi = ct0 * e0 + e1;
                invn[0] = 1.0 / sqrt(yr * yr + yi * yi);
            }
        }
        #undef STORE4
        #undef ADV
    }
}

// ---------------- K3: LDS-staged replay; regime-2 starts closed-form ----------------
__global__ __launch_bounds__(256) void k3_replay(const float* __restrict__ X,
        const float* tau, const float* omega, const float* a0, const float* b0,
        const float* __restrict__ s_in, const double* __restrict__ send1_ws,
        const double* __restrict__ t_ws, const double* __restrict__ invn,
        float* __restrict__ y_out, float* __restrict__ ysum_out) {
    __shared__ float2 ys[256 * 17];
    const int bx = blockIdx.x;
    const int b  = bx / NB3, blk = bx % NB3;
    const int j0 = blk * 256;
    const int nsub = (NS - j0 < 256) ? (NS - j0) : 256;
    int r1c = NS1 - j0; if (r1c < 0) r1c = 0; if (r1c > nsub) r1c = nsub;

    // coalesced X stage (regime-1 rows only), float4 granularity
    const int nld2 = r1c * 8;
    const float* xg = X + ((size_t)b * T_LEN + 1 + (size_t)j0 * SUB) * 2;
    for (int i2 = threadIdx.x; i2 < nld2; i2 += 256) {
        f4a8 v = *(const f4a8*)(xg + 4 * i2);
        int i = 2 * i2;
        *(f4a8*)&ys[(i >> 4) * 17 + (i & 15)] = v;
    }
    __syncthreads();

    double c, th0, th1; get_consts(tau, omega, c, th0, th1);
    const double inv = invn[0];
    const int tid = threadIdx.x;

    if (tid < nsub) {
        int j = j0 + tid;
        if (j < NS1) {
            float4 sv = *(const float4*)(s_in + ((size_t)b * NS1 + j) * 4);
            double R0 = sv.x, I0 = sv.y, R1 = sv.z, I1 = sv.w;
            Params P = make_params(c, th0, th1, (double)a0[0], (double)b0[0]);
            int len = (j < NS1 - 1) ? SUB : L1_LAST;
            #pragma unroll
            for (int s = 0; s < SUB; ++s) {
                if (s < len) {
                    float2 z = ys[tid * 17 + s];
                    step(P, R0, I0, R1, I1, (double)z.x, (double)z.y);
                    ys[tid * 17 + s] = make_float2((float)(R0 * inv), (float)(R1 * inv));
                }
            }
        } else {
            // regime-2 start: lam^(16m) * send1 (closed form, no s-load)
            int m = j - NS1;
            double e0 = send1_ws[b*4+0], e1 = send1_ws[b*4+1];
            double e2 = send1_ws[b*4+2], e3 = send1_ws[b*4+3];
            double q0r = 1.0, q0i = 0.0, q1r = 1.0, q1i = 0.0;
            #pragma unroll
            for (int k = 0; k < 10; ++k) {
                if (m & (1 << k)) {
                    double l0r = t_ws[T_LAM + (0*10+k)*2+0], l0i = t_ws[T_LAM + (0*10+k)*2+1];
                    double l1r = t_ws[T_LAM + (1*10+k)*2+0], l1i = t_ws[T_LAM + (1*10+k)*2+1];
                    double t0r = q0r*l0r - q0i*l0i, t0i = q0r*l0i + q0i*l0r;
                    double t1r = q1r*l1r - q1i*l1i, t1i = q1r*l1i + q1i*l1r;
                    q0r=t0r; q0i=t0i; q1r=t1r; q1i=t1i;
                }
            }
            double R0 = q0r * e0 - q0i * e1;
            double I0 = q0i * e0 + q0r * e1;
            double R1 = q1r * e2 - q1i * e3;
            double I1 = q1i * e2 + q1r * e3;
            Params P = make_params(c, th0, th1, 0.0, 0.0);
            #pragma unroll
            for (int s = 0; s < SUB; ++s) {
                step(P, R0, I0, R1, I1, 0.0, 0.0);
                ys[tid * 17 + s] = make_float2((float)(R0 * inv), (float)(R1 * inv));
            }
        }
    }
    __syncthreads();

    // coalesced vectorized store-out (pairs of consecutive t)
    float* yb = y_out + (size_t)b * T_LEN * 2;
    float* sb = ysum_out + (size_t)b * T_LEN;
    if (blk == 0 && threadIdx.x == 0) {
        yb[0] = 0.f; yb[1] = 0.f;   // y[:,0,:] = 0
        sb[0] = 0.f; sb[1] = 0.f;   // ysum[0] = 0; ysum[1] = sum(y[0]) = 0
    }
    const int npair = nsub * 8;
    for (int p = threadIdx.x; p < npair; p += 256) {
        int jj = p >> 3, s2 = (p & 7) * 2;
        int j = j0 + jj;
        float2 va = ys[jj * 17 + s2];
        float2 vb = ys[jj * 17 + s2 + 1];
        if (j < NS1) {
            int t = 1 + j * SUB + s2;
            if (j == NS1 - 1 && s2 + 1 >= L1_LAST) {   // s2==14: single element
                *(float2*)(yb + (size_t)t * 2) = va;
                sb[t + 1] = va.x + va.y;
            } else {
                f4a8 w = { va.x, va.y, vb.x, vb.y };
                *(f4a8*)(yb + (size_t)t * 2) = w;
                *(float2*)(sb + t + 1) = make_float2(va.x + va.y, vb.x + vb.y);
            }
        } else {
            int t = RESET_T + (j - NS1) * SUB + s2;
            f4a8 w = { va.x, va.y, vb.x, vb.y };
            *(f4a8*)(yb + (size_t)t * 2) = w;
            if (t + 1 < T_LEN) sb[t + 1] = va.x + va.y;
            if (t + 2 < T_LEN) sb[t + 2] = vb.x + vb.y;
        }
    }
}

extern "C" void kernel_launch(void* const* d_in, const int* in_sizes, int n_in,
                              void* d_out, int out_size, void* d_ws, size_t ws_size,
                              hipStream_t stream) {
    const float* X     = (const float*)d_in[0];
    const float* tau   = (const float*)d_in[1];
    const float* omega = (const float*)d_in[2];
    const float* a0    = (const float*)d_in[3];
    const float* b0    = (const float*)d_in[4];
    float* out = (float*)d_out;

    // Scratch in d_ws (~4 MB of 256 MiB); fully rewritten every call.
    double* t_ws  = (double*)d_ws;                       // T_TOTAL doubles (pad 256)
    double* send1 = t_ws + 256;                          // BATCH*4 doubles
    double* invn  = send1 + 256;                         // 1 double (pad 8)
    float*  p_ws  = (float*)(invn + 8);                  // [BATCH][NS1][4] fp32
    float*  s_ws  = p_ws + (size_t)BATCH * NS1 * 4;      // [BATCH][NS1][4] fp32

    k1_partial<<<BATCH * NB1, 256, 0, stream>>>(X, tau, omega, a0, b0, p_ws,
                                                out + B_OFF, out + A_OFF, t_ws);
    k2_scan_par<<<BATCH, 512, 0, stream>>>(tau, omega, a0, b0, p_ws, t_ws,
                                           s_ws, send1, invn);
    k3_replay<<<BATCH * NB3, 256, 0, stream>>>(X, tau, omega, a0, b0, s_ws, send1,
                                               t_ws, invn, out, out + YS_OFF);
}

// Round 14
// 31.728 us; speedup vs baseline: 4.0467x; 1.0262x over previous
//
#include <hip/hip_runtime.h>
#include <math.h>

#define T_LEN   40000
#define BATCH   64
#define RESET_T 30000
#define SUB     16
// regime 1: steps 1..29999 -> 1875 sub-chunks of 16 (1874 full, last = 15)
// regime 2: steps 30000..39999 -> 625 sub-chunks of 16 (all full)
#define NS1     1875
#define L1_LAST 15
#define NS2     625
#define NS      (NS1 + NS2)
// scan groups: 4 subs each (64 steps); groups 0..467 full, group 468 = 3 subs (47 steps)
#define NGFULL  468
#define NROUNDS 9
#define PI_D    3.14159265358979323846

#define NB1     8    // ceil(NS1/256): k1 blocks per batch
#define NB3     10   // ceil(NS /256): k3 blocks per batch

// uniform table (doubles at start of d_ws):
#define T_A16   0      // 3 mats: A^16, A^32, A^48
#define T_M64   48     // 9 mats: (A^64)^(2^r), r=0..8
#define T_A15   192    // 1 mat: A^15
#define T_LAM   208    // 2 osc * 10 * (re,im) = 40   (lam^(16*2^k))
#define T_TOTAL 248

// d_out layout in FLOATS (complex outputs validated as real part only):
#define Y_SIZE  ((size_t)BATCH * T_LEN * 2)
#define B_OFF   (Y_SIZE)
#define A_OFF   (B_OFF + T_LEN)
#define YS_OFF  (A_OFF + T_LEN)

// 16-byte vector with 8-byte alignment (regime-1 y stores land at odd-t*8B).
typedef struct __attribute__((aligned(8))) { float x, y, z, w; } f4a8;

struct Params { double alpha, beta, g0, g1, delta, k; };
struct ParamsF { float alpha, beta, g0, g1, delta, k; };

__device__ __forceinline__ Params make_params(double c, double th0, double th1,
                                              double a, double b) {
    double inva = 1.0 / (1.0 + a);
    double bb   = b / (1.0 + b);
    Params p;
    p.alpha = 1.0 + c * (inva - 1.0);
    p.beta  = 1.0 + c * (inva - 1.0 + bb);
    p.g0    = c * inva * th0;
    p.g1    = c * inva * th1;
    p.delta = c * bb;
    p.k     = c * bb;
    return p;
}

__device__ __forceinline__ ParamsF to_f(const Params& p) {
    ParamsF f;
    f.alpha = (float)p.alpha; f.beta = (float)p.beta;
    f.g0 = (float)p.g0; f.g1 = (float)p.g1;
    f.delta = (float)p.delta; f.k = (float)p.k;
    return f;
}

__device__ __forceinline__ void get_consts(const float* tau, const float* omega,
                                           double& c, double& th0, double& th1) {
    double tv = (double)tau[0];
    c   = 0.1 / tv;
    th0 = 2.0 * PI_D * tv * (double)omega[0];
    th1 = 2.0 * PI_D * tv * (double)omega[1];
}

// fp32 step: used in the 16-long chains of k1/k3 (error ~1e-6 rel per chunk,
// scan stays fp64; absmax is quantization-dominated — see round-13 evidence).
__device__ __forceinline__ void step_f(const ParamsF& P, float& R0, float& I0,
                                       float& R1, float& I1, float z0, float z1) {
    float nR0 = P.alpha * R0 - P.g0 * I0 - P.delta * R1 + P.k * z0;
    float nI0 = P.g0 * R0 + P.beta * I0;
    float nR1 = P.alpha * R1 - P.g1 * I1 - P.delta * R0 + P.k * z1;
    float nI1 = P.g1 * R1 + P.beta * I1;
    R0 = nR0; I0 = nI0; R1 = nR1; I1 = nI1;
}

__device__ __forceinline__ void matmul4(const double* A, const double* B, double* C) {
    for (int i = 0; i < 4; ++i)
        for (int jj = 0; jj < 4; ++jj) {
            double s = 0.0;
            for (int l = 0; l < 4; ++l) s += A[i * 4 + l] * B[l * 4 + jj];
            C[i * 4 + jj] = s;
        }
}

__device__ void build_A(const Params& P, double* A) {
    A[0]  = P.alpha; A[1]  = -P.g0;  A[2]  = -P.delta; A[3]  = 0.0;
    A[4]  = P.g0;    A[5]  = P.beta; A[6]  = 0.0;      A[7]  = 0.0;
    A[8]  = -P.delta;A[9]  = 0.0;    A[10] = P.alpha;  A[11] = -P.g1;
    A[12] = 0.0;     A[13] = 0.0;    A[14] = P.g1;     A[15] = P.beta;
}

// ---------------- K1: LDS-staged 16-step partials + b/a fill + table build ----------------
__global__ __launch_bounds__(256) void k1_partial(const float* __restrict__ X,
        const float* tau, const float* omega, const float* a0, const float* b0,
        float* __restrict__ p_out, float* __restrict__ b_out, float* __restrict__ a_out,
        double* __restrict__ t_ws) {
    __shared__ float2 xs[256 * 17];
    const int bx = blockIdx.x;
    const int b  = bx / NB1, blk = bx % NB1;
    const int j0 = blk * 256;
    const int nsub = (NS1 - j0 < 256) ? (NS1 - j0) : 256;
    const int gtid = bx * 256 + threadIdx.x;

    if (gtid < T_LEN) {
        b_out[gtid] = (gtid < RESET_T) ? b0[0] : 0.0f;
        a_out[gtid] = (gtid < RESET_T) ? a0[0] : 0.0f;
    }

    double c, th0, th1; get_consts(tau, omega, c, th0, th1);
    Params P = make_params(c, th0, th1, (double)a0[0], (double)b0[0]);

    if (gtid == 0) {
        double A1[16], A2m[16], A4m[16], A8m[16], tA12[16], tA14[16], tA15[16];
        build_A(P, A1);
        matmul4(A1, A1, A2m);
        matmul4(A2m, A2m, A4m);
        matmul4(A4m, A4m, A8m);
        matmul4(A8m, A8m, &t_ws[T_A16]);                         // A16
        matmul4(&t_ws[T_A16], &t_ws[T_A16], &t_ws[T_A16+16]);    // A32
        matmul4(&t_ws[T_A16+16], &t_ws[T_A16], &t_ws[T_A16+32]); // A48
        matmul4(&t_ws[T_A16+32], &t_ws[T_A16], &t_ws[T_M64]);    // A64
        for (int r = 1; r < NROUNDS; ++r)
            matmul4(&t_ws[T_M64 + (r-1)*16], &t_ws[T_M64 + (r-1)*16],
                    &t_ws[T_M64 + r*16]);
        matmul4(A8m, A4m, tA12);
        matmul4(tA12, A2m, tA14);
        matmul4(tA14, A1, tA15);                                 // A15
        for (int i = 0; i < 16; ++i) t_ws[T_A15 + i] = tA15[i];
        for (int o = 0; o < 2; ++o) {
            double ct = c * ((o == 0) ? th0 : th1);
            double lr = 1.0, li = ct;                            // lam^1
            for (int k = 0; k < 4; ++k) {                        // ^16
                double nr = lr*lr - li*li, ni = 2.0*lr*li; lr = nr; li = ni;
            }
            t_ws[T_LAM + (o*10 + 0)*2 + 0] = lr; t_ws[T_LAM + (o*10 + 0)*2 + 1] = li;
            for (int k = 1; k < 10; ++k) {
                double nr = lr*lr - li*li, ni = 2.0*lr*li; lr = nr; li = ni;
                t_ws[T_LAM + (o*10 + k)*2 + 0] = lr;
                t_ws[T_LAM + (o*10 + k)*2 + 1] = li;
            }
        }
    }

    // coalesced X stage, float4 granularity
    const int nld2 = nsub * 8;
    const float* xg = X + ((size_t)b * T_LEN + 1 + (size_t)j0 * SUB) * 2;
    for (int i2 = threadIdx.x; i2 < nld2; i2 += 256) {
        f4a8 v = *(const f4a8*)(xg + 4 * i2);
        int i = 2 * i2;
        *(f4a8*)&xs[(i >> 4) * 17 + (i & 15)] = v;
    }
    __syncthreads();

    const int tid = threadIdx.x;
    if (tid < nsub) {
        int j = j0 + tid;
        int len = (j < NS1 - 1) ? SUB : L1_LAST;
        ParamsF Pf = to_f(P);
        float R0 = 0.f, I0 = 0.f, R1 = 0.f, I1 = 0.f;
        #pragma unroll
        for (int s = 0; s < SUB; ++s) {
            if (s < len) {
                float2 z = xs[tid * 17 + s];
                step_f(Pf, R0, I0, R1, I1, z.x, z.y);
            }
        }
        *(float4*)(p_out + ((size_t)b * NS1 + j) * 4) =
            make_float4(R0, I0, R1, I1);
    }
}

// ---------------- K2: combine + Kogge-Stone + regime-1 expand; send1 out ----------------
__global__ __launch_bounds__(512) void k2_scan_par(const float* tau, const float* omega,
        const float* a0, const float* b0, const float* __restrict__ p_in,
        const double* __restrict__ t_ws,
        float* __restrict__ s_out, double* __restrict__ send1_ws,
        double* __restrict__ invn) {
    __shared__ double v[NGFULL * 5];      // stride 5: bank-conflict-free
    __shared__ double Tl[T_TOTAL];
    int b = blockIdx.x;
    int j = threadIdx.x;

    for (int i = j; i < T_TOTAL; i += 512) Tl[i] = t_ws[i];

    double c, th0, th1; get_consts(tau, omega, c, th0, th1);

    double p00=0,p01=0,p02=0,p03=0, p10=0,p11=0,p12=0,p13=0;
    double p20=0,p21=0,p22=0,p23=0, p30=0,p31=0,p32=0,p33=0;
    if (j <= NGFULL) {
        const float4* p = (const float4*)(p_in + ((size_t)b * NS1 + 4*j) * 4);
        float4 q0 = p[0], q1 = p[1], q2 = p[2];
        p00=q0.x; p01=q0.y; p02=q0.z; p03=q0.w;
        p10=q1.x; p11=q1.y; p12=q1.z; p13=q1.w;
        p20=q2.x; p21=q2.y; p22=q2.z; p23=q2.w;
        if (j < NGFULL) {
            float4 q3 = p[3];
            p30=q3.x; p31=q3.y; p32=q3.z; p33=q3.w;
        }
    }
    __syncthreads();

    if (j < NGFULL) {
        const double* M48 = &Tl[T_A16 + 32];
        const double* M32 = &Tl[T_A16 + 16];
        const double* M16 = &Tl[T_A16];
        #pragma unroll
        for (int i = 0; i < 4; ++i) {
            double s = (i==0?p30:i==1?p31:i==2?p32:p33);
            s += M48[i*4+0]*p00 + M48[i*4+1]*p01 + M48[i*4+2]*p02 + M48[i*4+3]*p03;
            s += M32[i*4+0]*p10 + M32[i*4+1]*p11 + M32[i*4+2]*p12 + M32[i*4+3]*p13;
            s += M16[i*4+0]*p20 + M16[i*4+1]*p21 + M16[i*4+2]*p22 + M16[i*4+3]*p23;
            v[j*5 + i] = s;
        }
    }
    __syncthreads();

    for (int r = 0, d = 1; r < NROUNDS; ++r, d <<= 1) {
        const double* M = &Tl[T_M64 + r * 16];
        double n0 = 0, n1 = 0, n2 = 0, n3 = 0;
        bool act = (j < NGFULL) && (j >= d);
        if (act) {
            const double* q = &v[(j - d) * 5];
            double q0 = q[0], q1 = q[1], q2 = q[2], q3 = q[3];
            const double* w = &v[j * 5];
            n0 = M[0]  * q0 + M[1]  * q1 + M[2]  * q2 + M[3]  * q3 + w[0];
            n1 = M[4]  * q0 + M[5]  * q1 + M[6]  * q2 + M[7]  * q3 + w[1];
            n2 = M[8]  * q0 + M[9]  * q1 + M[10] * q2 + M[11] * q3 + w[2];
            n3 = M[12] * q0 + M[13] * q1 + M[14] * q2 + M[15] * q3 + w[3];
        }
        __syncthreads();
        if (act) { v[j*5+0] = n0; v[j*5+1] = n1; v[j*5+2] = n2; v[j*5+3] = n3; }
        __syncthreads();
    }

    if (j <= NGFULL) {
        const double* A16m = &Tl[T_A16];
        double s0 = 0, s1 = 0, s2 = 0, s3 = 0;
        if (j > 0) { s0=v[(j-1)*5+0]; s1=v[(j-1)*5+1]; s2=v[(j-1)*5+2]; s3=v[(j-1)*5+3]; }
        float4* so = (float4*)(s_out + ((size_t)b * NS1 + 4*j) * 4);
        #define STORE4(off) { so[off] = make_float4((float)s0,(float)s1,(float)s2,(float)s3); }
        #define ADV(q0,q1,q2,q3) { \
            double a_ = A16m[0]*s0 + A16m[1]*s1 + A16m[2]*s2 + A16m[3]*s3 + q0; \
            double b_ = A16m[4]*s0 + A16m[5]*s1 + A16m[6]*s2 + A16m[7]*s3 + q1; \
            double c_ = A16m[8]*s0 + A16m[9]*s1 + A16m[10]*s2 + A16m[11]*s3 + q2; \
            double d_ = A16m[12]*s0 + A16m[13]*s1 + A16m[14]*s2 + A16m[15]*s3 + q3; \
            s0=a_; s1=b_; s2=c_; s3=d_; }
        if (j < NGFULL) {
            STORE4(0);
            ADV(p00,p01,p02,p03); STORE4(1);
            ADV(p10,p11,p12,p13); STORE4(2);
            ADV(p20,p21,p22,p23); STORE4(3);
        } else {
            STORE4(0);
            ADV(p00,p01,p02,p03); STORE4(1);
            ADV(p10,p11,p12,p13); STORE4(2);
            const double* A15m = &Tl[T_A15];
            double e0 = A15m[0]*s0 + A15m[1]*s1 + A15m[2]*s2 + A15m[3]*s3 + p20;
            double e1 = A15m[4]*s0 + A15m[5]*s1 + A15m[6]*s2 + A15m[7]*s3 + p21;
            double e2 = A15m[8]*s0 + A15m[9]*s1 + A15m[10]*s2 + A15m[11]*s3 + p22;
            double e3 = A15m[12]*s0 + A15m[13]*s1 + A15m[14]*s2 + A15m[15]*s3 + p23;
            send1_ws[b*4+0]=e0; send1_ws[b*4+1]=e1;
            send1_ws[b*4+2]=e2; send1_ws[b*4+3]=e3;
            if (b == 0) {
                double ct0 = c * th0;   // y[0,RESET_T,0] = (1 + j*c*th0)*(e0 + j*e1)
                double yr = e0 - ct0 * e1;
                double yi = ct0 * e0 + e1;
                invn[0] = 1.0 / sqrt(yr * yr + yi * yi);
            }
        }
        #undef STORE4
        #undef ADV
    }
}

// ---------------- K3: LDS-staged replay; regime-2 starts closed-form ----------------
__global__ __launch_bounds__(256) void k3_replay(const float* __restrict__ X,
        const float* tau, const float* omega, const float* a0, const float* b0,
        const float* __restrict__ s_in, const double* __restrict__ send1_ws,
        const double* __restrict__ t_ws, const double* __restrict__ invn,
        float* __restrict__ y_out, float* __restrict__ ysum_out) {
    __shared__ float2 ys[256 * 17];
    const int bx = blockIdx.x;
    const int b  = bx / NB3, blk = bx % NB3;
    const int j0 = blk * 256;
    const int nsub = (NS - j0 < 256) ? (NS - j0) : 256;
    int r1c = NS1 - j0; if (r1c < 0) r1c = 0; if (r1c > nsub) r1c = nsub;

    // coalesced X stage (regime-1 rows only), float4 granularity
    const int nld2 = r1c * 8;
    const float* xg = X + ((size_t)b * T_LEN + 1 + (size_t)j0 * SUB) * 2;
    for (int i2 = threadIdx.x; i2 < nld2; i2 += 256) {
        f4a8 v = *(const f4a8*)(xg + 4 * i2);
        int i = 2 * i2;
        *(f4a8*)&ys[(i >> 4) * 17 + (i & 15)] = v;
    }
    __syncthreads();

    double c, th0, th1; get_consts(tau, omega, c, th0, th1);
    const float invf = (float)invn[0];
    const int tid = threadIdx.x;

    if (tid < nsub) {
        int j = j0 + tid;
        if (j < NS1) {
            float4 sv = *(const float4*)(s_in + ((size_t)b * NS1 + j) * 4);
            float R0 = sv.x, I0 = sv.y, R1 = sv.z, I1 = sv.w;
            ParamsF Pf = to_f(make_params(c, th0, th1, (double)a0[0], (double)b0[0]));
            int len = (j < NS1 - 1) ? SUB : L1_LAST;
            #pragma unroll
            for (int s = 0; s < SUB; ++s) {
                if (s < len) {
                    float2 z = ys[tid * 17 + s];
                    step_f(Pf, R0, I0, R1, I1, z.x, z.y);
                    ys[tid * 17 + s] = make_float2(R0 * invf, R1 * invf);
                }
            }
        } else {
            // regime-2 start: lam^(16m) * send1 (closed form, fp64), then fp32 chain
            int m = j - NS1;
            double e0 = send1_ws[b*4+0], e1 = send1_ws[b*4+1];
            double e2 = send1_ws[b*4+2], e3 = send1_ws[b*4+3];
            double q0r = 1.0, q0i = 0.0, q1r = 1.0, q1i = 0.0;
            #pragma unroll
            for (int k = 0; k < 10; ++k) {
                if (m & (1 << k)) {
                    double l0r = t_ws[T_LAM + (0*10+k)*2+0], l0i = t_ws[T_LAM + (0*10+k)*2+1];
                    double l1r = t_ws[T_LAM + (1*10+k)*2+0], l1i = t_ws[T_LAM + (1*10+k)*2+1];
                    double t0r = q0r*l0r - q0i*l0i, t0i = q0r*l0i + q0i*l0r;
                    double t1r = q1r*l1r - q1i*l1i, t1i = q1r*l1i + q1i*l1r;
                    q0r=t0r; q0i=t0i; q1r=t1r; q1i=t1i;
                }
            }
            float R0 = (float)(q0r * e0 - q0i * e1);
            float I0 = (float)(q0i * e0 + q0r * e1);
            float R1 = (float)(q1r * e2 - q1i * e3);
            float I1 = (float)(q1i * e2 + q1r * e3);
            ParamsF Pf = to_f(make_params(c, th0, th1, 0.0, 0.0));
            #pragma unroll
            for (int s = 0; s < SUB; ++s) {
                step_f(Pf, R0, I0, R1, I1, 0.f, 0.f);
                ys[tid * 17 + s] = make_float2(R0 * invf, R1 * invf);
            }
        }
    }
    __syncthreads();

    // coalesced vectorized store-out (pairs of consecutive t)
    float* yb = y_out + (size_t)b * T_LEN * 2;
    float* sb = ysum_out + (size_t)b * T_LEN;
    if (blk == 0 && threadIdx.x == 0) {
        yb[0] = 0.f; yb[1] = 0.f;   // y[:,0,:] = 0
        sb[0] = 0.f; sb[1] = 0.f;   // ysum[0] = 0; ysum[1] = sum(y[0]) = 0
    }
    const int npair = nsub * 8;
    for (int p = threadIdx.x; p < npair; p += 256) {
        int jj = p >> 3, s2 = (p & 7) * 2;
        int j = j0 + jj;
        float2 va = ys[jj * 17 + s2];
        float2 vb = ys[jj * 17 + s2 + 1];
        if (j < NS1) {
            int t = 1 + j * SUB + s2;
            if (j == NS1 - 1 && s2 + 1 >= L1_LAST) {   // s2==14: single element
                *(float2*)(yb + (size_t)t * 2) = va;
                sb[t + 1] = va.x + va.y;
            } else {
                f4a8 w = { va.x, va.y, vb.x, vb.y };
                *(f4a8*)(yb + (size_t)t * 2) = w;
                *(float2*)(sb + t + 1) = make_float2(va.x + va.y, vb.x + vb.y);
            }
        } else {
            int t = RESET_T + (j - NS1) * SUB + s2;
            f4a8 w = { va.x, va.y, vb.x, vb.y };
            *(f4a8*)(yb + (size_t)t * 2) = w;
            if (t + 1 < T_LEN) sb[t + 1] = va.x + va.y;
            if (t + 2 < T_LEN) sb[t + 2] = vb.x + vb.y;
        }
    }
}

extern "C" void kernel_launch(void* const* d_in, const int* in_sizes, int n_in,
                              void* d_out, int out_size, void* d_ws, size_t ws_size,
                              hipStream_t stream) {
    const float* X     = (const float*)d_in[0];
    const float* tau   = (const float*)d_in[1];
    const float* omega = (const float*)d_in[2];
    const float* a0    = (const float*)d_in[3];
    const float* b0    = (const float*)d_in[4];
    float* out = (float*)d_out;

    // Scratch in d_ws (~4 MB of 256 MiB); fully rewritten every call.
    double* t_ws  = (double*)d_ws;                       // T_TOTAL doubles (pad 256)
    double* send1 = t_ws + 256;                          // BATCH*4 doubles
    double* invn  = send1 + 256;                         // 1 double (pad 8)
    float*  p_ws  = (float*)(invn + 8);                  // [BATCH][NS1][4] fp32
    float*  s_ws  = p_ws + (size_t)BATCH * NS1 * 4;      // [BATCH][NS1][4] fp32

    k1_partial<<<BATCH * NB1, 256, 0, stream>>>(X, tau, omega, a0, b0, p_ws,
                                                out + B_OFF, out + A_OFF, t_ws);
    k2_scan_par<<<BATCH, 512, 0, stream>>>(tau, omega, a0, b0, p_ws, t_ws,
                                           s_ws, send1, invn);
    k3_replay<<<BATCH * NB3, 256, 0, stream>>>(X, tau, omega, a0, b0, s_ws, send1,
                                               t_ws, invn, out, out + YS_OFF);
}